// Round 6
// baseline (789.190 us; speedup 1.0000x reference)
//
#include <hip/hip_runtime.h>

typedef __attribute__((ext_vector_type(8))) short short8;
typedef __attribute__((ext_vector_type(4))) short short4v;
typedef __attribute__((ext_vector_type(4))) float f32x4;

__device__ __forceinline__ unsigned short f2bf(float f) {
  unsigned int u = __float_as_uint(f);
  u += 0x7fffu + ((u >> 16) & 1u);   // RNE round to bf16
  return (unsigned short)(u >> 16);
}
__device__ __forceinline__ float bf2f(unsigned short u) {
  return __uint_as_float(((unsigned int)u) << 16);
}
__device__ __forceinline__ float sigm(float x) { return 1.f / (1.f + expf(-x)); }

// ---------------------------------------------------------------------------
// Skinny GEMM core: 112(M) x 64(N) per block, K = NKC*256 per z-chunk.
// X staged to LDS in MFMA-fragment order; 8-deep W burst per chunk.
// gemm_v5  : bf16 W, bf16 partial out (split-K)
// gemm_v5f : f32  W, bf16 partial out (split-K)
// gemm_dwf : f32  W, direct f32 out + bias (z=1)
// gemm_dwf_split : f32 W1/W2 (cat), f32 out + bias for cols<NS, bf16 aux after
// ---------------------------------------------------------------------------
template<int NKC>
__global__ __launch_bounds__(256) void gemm_v5(
    const unsigned short* __restrict__ X, int ldx,
    const unsigned short* __restrict__ W, int ldw, int N,
    unsigned short* __restrict__ C, long long slotStride)
{
  __shared__ short8 lds[3584];
  const int tid = threadIdx.x;
  const int lane = tid & 63, wv = tid >> 6;
  const int l16 = lane & 15, kg = (lane >> 4) * 8;
  const int mbase = blockIdx.y * 112;
  const int ncol = blockIdx.x * 64 + wv * 16 + l16;
  const int nrow = (ncol < N) ? ncol : (N - 1);
  const long long k0 = (long long)blockIdx.z * (NKC * 256);
  C += (long long)blockIdx.z * slotStride;

  const unsigned short* wp = W + (size_t)nrow * ldw + kg + k0;
  const unsigned short* xb = X + (size_t)(mbase + l16) * ldx + kg + k0;
  const size_t xrow = (size_t)16 * ldx;

  f32x4 acc[7];
#pragma unroll
  for (int i = 0; i < 7; ++i) acc[i] = (f32x4){0.f, 0.f, 0.f, 0.f};

  for (int kc = 0; kc < NKC; ++kc) {
    if (kc) __syncthreads();
    short8 wbuf[8];
#pragma unroll
    for (int ks = 0; ks < 8; ++ks)
      wbuf[ks] = *(const short8*)(wp + kc * 256 + ks * 32);
    short8 xst[14];
#pragma unroll
    for (int i = 0; i < 14; ++i) {
      const int f = wv + i * 4, mt = f >> 3, ks = f & 7;
      xst[i] = *(const short8*)(xb + (size_t)mt * xrow + kc * 256 + ks * 32);
    }
#pragma unroll
    for (int i = 0; i < 14; ++i) lds[(wv + i * 4) * 64 + lane] = xst[i];
    __syncthreads();
#pragma unroll
    for (int ks = 0; ks < 8; ++ks)
#pragma unroll
      for (int mt = 0; mt < 7; ++mt) {
        short8 a = lds[(mt * 8 + ks) * 64 + lane];
        acc[mt] = __builtin_amdgcn_mfma_f32_16x16x32_bf16(a, wbuf[ks], acc[mt], 0, 0, 0);
      }
  }
  if (ncol < N) {
    const int r0 = (lane >> 4) * 4;
#pragma unroll
    for (int mt = 0; mt < 7; ++mt)
#pragma unroll
      for (int r = 0; r < 4; ++r)
        C[(size_t)(mbase + mt * 16 + r0 + r) * N + ncol] = f2bf(acc[mt][r]);
  }
}

template<int NKC>
__global__ __launch_bounds__(256) void gemm_v5f(
    const unsigned short* __restrict__ X, int ldx,
    const float* __restrict__ W, int ldw, int N,
    unsigned short* __restrict__ C, long long slotStride)
{
  __shared__ short8 lds[3584];
  const int tid = threadIdx.x;
  const int lane = tid & 63, wv = tid >> 6;
  const int l16 = lane & 15, kg = (lane >> 4) * 8;
  const int mbase = blockIdx.y * 112;
  const int ncol = blockIdx.x * 64 + wv * 16 + l16;
  const int nrow = (ncol < N) ? ncol : (N - 1);
  const long long k0 = (long long)blockIdx.z * (NKC * 256);
  C += (long long)blockIdx.z * slotStride;

  const float* wp = W + (size_t)nrow * ldw + kg + k0;
  const unsigned short* xb = X + (size_t)(mbase + l16) * ldx + kg + k0;
  const size_t xrow = (size_t)16 * ldx;

  f32x4 acc[7];
#pragma unroll
  for (int i = 0; i < 7; ++i) acc[i] = (f32x4){0.f, 0.f, 0.f, 0.f};

  for (int kc = 0; kc < NKC; ++kc) {
    if (kc) __syncthreads();
    float4 wa[8], wb[8];
#pragma unroll
    for (int ks = 0; ks < 8; ++ks) {
      wa[ks] = *(const float4*)(wp + kc * 256 + ks * 32);
      wb[ks] = *(const float4*)(wp + kc * 256 + ks * 32 + 4);
    }
    short8 xst[14];
#pragma unroll
    for (int i = 0; i < 14; ++i) {
      const int f = wv + i * 4, mt = f >> 3, ks = f & 7;
      xst[i] = *(const short8*)(xb + (size_t)mt * xrow + kc * 256 + ks * 32);
    }
#pragma unroll
    for (int i = 0; i < 14; ++i) lds[(wv + i * 4) * 64 + lane] = xst[i];
    __syncthreads();
#pragma unroll
    for (int ks = 0; ks < 8; ++ks) {
      short8 w;
      w[0] = (short)f2bf(wa[ks].x); w[1] = (short)f2bf(wa[ks].y);
      w[2] = (short)f2bf(wa[ks].z); w[3] = (short)f2bf(wa[ks].w);
      w[4] = (short)f2bf(wb[ks].x); w[5] = (short)f2bf(wb[ks].y);
      w[6] = (short)f2bf(wb[ks].z); w[7] = (short)f2bf(wb[ks].w);
#pragma unroll
      for (int mt = 0; mt < 7; ++mt) {
        short8 a = lds[(mt * 8 + ks) * 64 + lane];
        acc[mt] = __builtin_amdgcn_mfma_f32_16x16x32_bf16(a, w, acc[mt], 0, 0, 0);
      }
    }
  }
  if (ncol < N) {
    const int r0 = (lane >> 4) * 4;
#pragma unroll
    for (int mt = 0; mt < 7; ++mt)
#pragma unroll
      for (int r = 0; r < 4; ++r)
        C[(size_t)(mbase + mt * 16 + r0 + r) * N + ncol] = f2bf(acc[mt][r]);
  }
}

template<int NKC>
__global__ __launch_bounds__(256) void gemm_dwf(
    const unsigned short* __restrict__ X, int ldx,
    const float* __restrict__ W, int ldw, int N,
    float* __restrict__ outF, const float* __restrict__ bias,
    long long ldc, int rowLim)
{
  __shared__ short8 lds[3584];
  const int tid = threadIdx.x;
  const int lane = tid & 63, wv = tid >> 6;
  const int l16 = lane & 15, kg = (lane >> 4) * 8;
  const int mbase = blockIdx.y * 112;
  const int ncol = blockIdx.x * 64 + wv * 16 + l16;
  const int nrow = (ncol < N) ? ncol : (N - 1);

  const float* wp = W + (size_t)nrow * ldw + kg;
  const unsigned short* xb = X + (size_t)(mbase + l16) * ldx + kg;
  const size_t xrow = (size_t)16 * ldx;

  f32x4 acc[7];
#pragma unroll
  for (int i = 0; i < 7; ++i) acc[i] = (f32x4){0.f, 0.f, 0.f, 0.f};

  for (int kc = 0; kc < NKC; ++kc) {
    if (kc) __syncthreads();
    float4 wa[8], wb[8];
#pragma unroll
    for (int ks = 0; ks < 8; ++ks) {
      wa[ks] = *(const float4*)(wp + kc * 256 + ks * 32);
      wb[ks] = *(const float4*)(wp + kc * 256 + ks * 32 + 4);
    }
    short8 xst[14];
#pragma unroll
    for (int i = 0; i < 14; ++i) {
      const int f = wv + i * 4, mt = f >> 3, ks = f & 7;
      xst[i] = *(const short8*)(xb + (size_t)mt * xrow + kc * 256 + ks * 32);
    }
#pragma unroll
    for (int i = 0; i < 14; ++i) lds[(wv + i * 4) * 64 + lane] = xst[i];
    __syncthreads();
#pragma unroll
    for (int ks = 0; ks < 8; ++ks) {
      short8 w;
      w[0] = (short)f2bf(wa[ks].x); w[1] = (short)f2bf(wa[ks].y);
      w[2] = (short)f2bf(wa[ks].z); w[3] = (short)f2bf(wa[ks].w);
      w[4] = (short)f2bf(wb[ks].x); w[5] = (short)f2bf(wb[ks].y);
      w[6] = (short)f2bf(wb[ks].z); w[7] = (short)f2bf(wb[ks].w);
#pragma unroll
      for (int mt = 0; mt < 7; ++mt) {
        short8 a = lds[(mt * 8 + ks) * 64 + lane];
        acc[mt] = __builtin_amdgcn_mfma_f32_16x16x32_bf16(a, w, acc[mt], 0, 0, 0);
      }
    }
  }
  if (ncol < N) {
    const float bv = bias ? bias[ncol] : 0.f;
    const int r0 = (lane >> 4) * 4;
#pragma unroll
    for (int mt = 0; mt < 7; ++mt)
#pragma unroll
      for (int r = 0; r < 4; ++r) {
        const int row = mbase + mt * 16 + r0 + r;
        if (row < rowLim) outF[(size_t)row * ldc + ncol] = acc[mt][r] + bv;
      }
  }
}

// cat = [W_fc1 ; W_dec]: cols<10000 -> f32 out (+bias), cols>=10000 -> bf16 aux
template<int NKC>
__global__ __launch_bounds__(256) void gemm_dwf_split(
    const unsigned short* __restrict__ X, int ldx,
    const float* __restrict__ W1, const float* __restrict__ W2,
    float* __restrict__ outF, const float* __restrict__ bias,
    unsigned short* __restrict__ aux)
{
  __shared__ short8 lds[3584];
  const int tid = threadIdx.x;
  const int lane = tid & 63, wv = tid >> 6;
  const int l16 = lane & 15, kg = (lane >> 4) * 8;
  const int ncol0 = blockIdx.x * 64 + wv * 16 + l16;
  const int ncol = (ncol0 < 10512) ? ncol0 : 10511;
  const float* wp = ((ncol < 10000) ? W1 + (size_t)ncol * 1024
                                    : W2 + (size_t)(ncol - 10000) * 1024) + kg;
  const unsigned short* xb = X + (size_t)l16 * ldx + kg;
  const size_t xrow = (size_t)16 * ldx;

  f32x4 acc[7];
#pragma unroll
  for (int i = 0; i < 7; ++i) acc[i] = (f32x4){0.f, 0.f, 0.f, 0.f};

  for (int kc = 0; kc < NKC; ++kc) {
    if (kc) __syncthreads();
    float4 wa[8], wb[8];
#pragma unroll
    for (int ks = 0; ks < 8; ++ks) {
      wa[ks] = *(const float4*)(wp + kc * 256 + ks * 32);
      wb[ks] = *(const float4*)(wp + kc * 256 + ks * 32 + 4);
    }
    short8 xst[14];
#pragma unroll
    for (int i = 0; i < 14; ++i) {
      const int f = wv + i * 4, mt = f >> 3, ks = f & 7;
      xst[i] = *(const short8*)(xb + (size_t)mt * xrow + kc * 256 + ks * 32);
    }
#pragma unroll
    for (int i = 0; i < 14; ++i) lds[(wv + i * 4) * 64 + lane] = xst[i];
    __syncthreads();
#pragma unroll
    for (int ks = 0; ks < 8; ++ks) {
      short8 w;
      w[0] = (short)f2bf(wa[ks].x); w[1] = (short)f2bf(wa[ks].y);
      w[2] = (short)f2bf(wa[ks].z); w[3] = (short)f2bf(wa[ks].w);
      w[4] = (short)f2bf(wb[ks].x); w[5] = (short)f2bf(wb[ks].y);
      w[6] = (short)f2bf(wb[ks].z); w[7] = (short)f2bf(wb[ks].w);
#pragma unroll
      for (int mt = 0; mt < 7; ++mt) {
        short8 a = lds[(mt * 8 + ks) * 64 + lane];
        acc[mt] = __builtin_amdgcn_mfma_f32_16x16x32_bf16(a, w, acc[mt], 0, 0, 0);
      }
    }
  }
  if (ncol0 < 10000) {
    const float bv = bias[ncol0];
    const int r0 = (lane >> 4) * 4;
#pragma unroll
    for (int mt = 0; mt < 7; ++mt)
#pragma unroll
      for (int r = 0; r < 4; ++r) {
        const int row = mt * 16 + r0 + r;
        if (row < 100) outF[(size_t)row * 50000 + ncol0] = acc[mt][r] + bv;
      }
  } else if (ncol0 < 10512) {
    const int r0 = (lane >> 4) * 4;
#pragma unroll
    for (int mt = 0; mt < 7; ++mt)
#pragma unroll
      for (int r = 0; r < 4; ++r)
        aux[(size_t)(mt * 16 + r0 + r) * 512 + (ncol0 - 10000)] = f2bf(acc[mt][r]);
  }
}

// ------------------- fused weight pack (Wg1, Wg2, Wtop only) ----------------
__global__ __launch_bounds__(256) void k_pack_all(
    const float* __restrict__ Wih1, const float* __restrict__ Whh1,
    const float* __restrict__ Wih2, const float* __restrict__ Whh2,
    const float* __restrict__ Wtop,
    unsigned short* __restrict__ Wg1, unsigned short* __restrict__ Wg2,
    unsigned short* __restrict__ Wtopb)
{
  int i = blockIdx.x * 256 + threadIdx.x;            // 8,454,144 vec4 total
  float4 v; unsigned short* dst; long long di;
  if (i < 2097152) {                                  // Wg1 = [Wih1.h2 | Whh1]
    int row = i >> 9, c4 = i & 511;
    const float* s = (c4 < 256) ? Wih1 + (size_t)row * 6144 + c4 * 4
                                : Whh1 + (size_t)row * 1024 + (c4 - 256) * 4;
    v = *(const float4*)s; dst = Wg1; di = i;
  } else if (i < 8388608) {                           // Wg2 = [Wih2 | Whh2]
    int j = i - 2097152; int row = j / 1536, c4 = j - row * 1536;
    const float* s = (c4 < 1280) ? Wih2 + (size_t)row * 5120 + c4 * 4
                                 : Whh2 + (size_t)row * 1024 + (c4 - 1280) * 4;
    v = *(const float4*)s; dst = Wg2; di = j;
  } else {                                            // Wtopb 512x512, K-pad
    int j = i - 8388608; if (j >= 65536) return;
    int n = j >> 7, c4 = j & 127;
    v = (c4 < 125) ? *(const float4*)(Wtop + (size_t)n * 500 + c4 * 4)
                   : (float4){0.f, 0.f, 0.f, 0.f};
    dst = Wtopb; di = j;
  }
  short4v o; o[0] = (short)f2bf(v.x); o[1] = (short)f2bf(v.y);
  o[2] = (short)f2bf(v.z); o[3] = (short)f2bf(v.w);
  ((short4v*)dst)[di] = o;
}

// --------------------------- phase-A helper kernels ------------------------
// img -> bf16 copy + per-(b,f) mean over 15 regions, one read of imgf
__global__ __launch_bounds__(256) void k_ximg2(const float* __restrict__ img,
    unsigned short* __restrict__ Ximg, unsigned short* __restrict__ Xmean) {
  int idx = blockIdx.x * 256 + threadIdx.x;          // 100*4096
  int b = idx >> 12, f = idx & 4095;
  float s = 0.f;
#pragma unroll
  for (int r = 0; r < 15; ++r) {
    float v = img[((size_t)(b * 15 + r) << 12) + f];
    s += v;
    Ximg[((size_t)(b * 15 + r) << 12) + f] = f2bf(v);
  }
  Xmean[((size_t)b << 12) + f] = f2bf(s * (1.f / 15.f));
}

__global__ __launch_bounds__(512) void k_conv(const float* __restrict__ lin,
    const float* __restrict__ cw, const float* __restrict__ cb,
    float* __restrict__ topics) {
  int b = blockIdx.x;
  __shared__ float L[15 * 1024];
  for (int i = threadIdx.x; i < 15 * 1024; i += 512) L[i] = lin[(size_t)b * 15360 + i];
  __syncthreads();
  for (int idx = threadIdx.x; idx < 2500; idx += 512) {
    int tt = idx / 500, w = idx - tt * 500;
    float s = cb[tt];
    for (int kh = 0; kh < 15; ++kh) {
      const float* lr = &L[kh * 1024 + 2 * w];
      const float* wr = &cw[(tt * 15 + kh) * 26];
#pragma unroll
      for (int kw = 0; kw < 26; ++kw) s += lr[kw] * wr[kw];
    }
    topics[(size_t)b * 2500 + idx] = s;
  }
}

__global__ __launch_bounds__(256) void k_padtop(const float* __restrict__ topics,
    unsigned short* __restrict__ Xtop) {
  int idx = blockIdx.x * 256 + threadIdx.x;          // 560*512
  if (idx >= 560 * 512) return;
  int r = idx >> 9, k = idx & 511;
  Xtop[idx] = (r < 500 && k < 500) ? f2bf(topics[(size_t)r * 500 + k]) : (unsigned short)0;
}

__global__ void k_wc(const int* __restrict__ caps, const int* __restrict__ lens,
                     int* __restrict__ words, float* __restrict__ out2,
                     float* __restrict__ out3) {
  int idx = blockIdx.x * 256 + threadIdx.x;
  if (idx < 26000) out2[idx] = (float)caps[idx];
  if (idx < 500) {
    int len = lens[idx];
    words[idx] = caps[idx * 52 + len - 1];
    out3[idx] = (float)(len - 1);
  }
}

__global__ __launch_bounds__(256) void k_gather(const float* __restrict__ emb,
    const int* __restrict__ words, unsigned short* __restrict__ Xemb) {
  int idx = blockIdx.x * 256 + threadIdx.x;          // 560*1024
  int bt = idx >> 10, e = idx & 1023;
  Xemb[idx] = (bt < 500) ? f2bf(emb[(size_t)words[bt] * 1024 + e]) : (unsigned short)0;
}

__global__ __launch_bounds__(256) void k_gbase1(const unsigned short* __restrict__ P,
    const float* __restrict__ bih, const float* __restrict__ bhh,
    float* __restrict__ gb) {
  int idx = blockIdx.x * 256 + threadIdx.x;          // 112*4096
  int m = idx >> 12, n = idx & 4095;
  float s = bih[n] + bhh[n];
#pragma unroll
  for (int sl = 0; sl < 4; ++sl) s += bf2f(P[((size_t)sl * 112 + m) * 4096 + n]);
  gb[idx] = s;
}

// ------------------------------ per-step kernels ---------------------------
__global__ __launch_bounds__(256) void k_lstm1(const unsigned short* __restrict__ P,
    const float* __restrict__ gb1, const float* __restrict__ gemb, int t,
    float* __restrict__ c1, unsigned short* __restrict__ Xh1,
    unsigned short* __restrict__ X1, unsigned short* __restrict__ X2) {
  int idx = blockIdx.x * 256 + threadIdx.x;          // 100*1024
  int b = idx >> 10, j = idx & 1023;
  float g[4];
#pragma unroll
  for (int x = 0; x < 4; ++x) {
    int col = (x << 10) + j;
    float s = gb1[b * 4096 + col] + gemb[((size_t)b * 5 + t) * 4096 + col];
#pragma unroll
    for (int sl = 0; sl < 4; ++sl) s += bf2f(P[((size_t)sl * 112 + b) * 4096 + col]);
    g[x] = s;
  }
  float c = sigm(g[1]) * c1[idx] + sigm(g[0]) * tanhf(g[2]);
  float h = sigm(g[3]) * tanhf(c);
  c1[idx] = c;
  unsigned short hb = f2bf(h);
  Xh1[idx] = hb;
  X1[b * 2048 + 1024 + j] = hb;
  X2[(size_t)b * 6144 + 4096 + j] = hb;
}

__global__ __launch_bounds__(256) void k_attawe(const float* __restrict__ att1,
    const unsigned short* __restrict__ padec, const float* __restrict__ bdec,
    const float* __restrict__ btop, const unsigned short* __restrict__ ttopb,
    const float* __restrict__ wfull, int t,
    const unsigned short* __restrict__ Ximg, unsigned short* __restrict__ X2) {
  int b = blockIdx.x;
  int tid = threadIdx.x;
  int r = tid & 15, ch = tid >> 4;                   // 15 regions x 16 chunks
  __shared__ float sp[16][17];
  __shared__ float al[16];
  float s = 0.f;
  if (r < 15) {
    const float* a1 = att1 + ((size_t)b * 15 + r) * 512;
    const unsigned short* tp = ttopb + ((size_t)b * 5 + t) * 512;
#pragma unroll
    for (int j = 0; j < 32; ++j) {
      int n = ch * 32 + j;
      float ad = bdec[n] + btop[n] + bf2f(padec[(size_t)b * 512 + n]);
      float v = a1[n] + ad + bf2f(tp[n]);
      s += fmaxf(v, 0.f) * wfull[n];
    }
  }
  sp[r][ch] = s;
  __syncthreads();
  if (tid == 0) {
    float sc[15];
    float m = -1e30f;
    for (int rr = 0; rr < 15; ++rr) {
      float x = 0.f;
      for (int cc = 0; cc < 16; ++cc) x += sp[rr][cc];
      sc[rr] = x; m = fmaxf(m, x);
    }
    float sum = 0.f;
    for (int rr = 0; rr < 15; ++rr) { sc[rr] = expf(sc[rr] - m); sum += sc[rr]; }
    float inv = 1.f / sum;
    for (int rr = 0; rr < 15; ++rr) al[rr] = sc[rr] * inv;
  }
  __syncthreads();
  for (int f = tid; f < 4096; f += 256) {
    float s2 = 0.f;
#pragma unroll
    for (int rr = 0; rr < 15; ++rr)
      s2 += al[rr] * bf2f(Ximg[((size_t)b * 15 + rr) * 4096 + f]);
    X2[(size_t)b * 6144 + f] = f2bf(s2);
  }
}

__global__ __launch_bounds__(256) void k_lstm2(const unsigned short* __restrict__ P,
    const float* __restrict__ bih, const float* __restrict__ bhh,
    float* __restrict__ c2, unsigned short* __restrict__ Xh2,
    unsigned short* __restrict__ X1, unsigned short* __restrict__ X2) {
  int idx = blockIdx.x * 256 + threadIdx.x;          // 100*1024
  int b = idx >> 10, j = idx & 1023;
  float g[4];
#pragma unroll
  for (int x = 0; x < 4; ++x) {
    int col = (x << 10) + j;
    float s = bih[col] + bhh[col];
#pragma unroll
    for (int sl = 0; sl < 6; ++sl) s += bf2f(P[((size_t)sl * 112 + b) * 4096 + col]);
    g[x] = s;
  }
  float c = sigm(g[1]) * c2[idx] + sigm(g[0]) * tanhf(g[2]);
  float h = sigm(g[3]) * tanhf(c);
  c2[idx] = c;
  unsigned short hb = f2bf(h);
  Xh2[idx] = hb;
  X1[b * 2048 + j] = hb;
  X2[(size_t)b * 6144 + 5120 + j] = hb;
}

// ---------------------------------------------------------------------------
extern "C" void kernel_launch(void* const* d_in, const int* in_sizes, int n_in,
                              void* d_out, int out_size, void* d_ws, size_t ws_size,
                              hipStream_t stream) {
  (void)in_sizes; (void)n_in; (void)out_size;
  const float* imgf  = (const float*)d_in[0];
  const int*   caps  = (const int*)d_in[1];
  const int*   lens  = (const int*)d_in[2];
  const float* W_lt  = (const float*)d_in[3];
  const float* b_lt  = (const float*)d_in[4];
  const float* convw = (const float*)d_in[5];
  const float* convb = (const float*)d_in[6];
  const float* W_feat = (const float*)d_in[7];
  const float* b_feat = (const float*)d_in[8];
  const float* W_dec = (const float*)d_in[9];
  const float* b_dec = (const float*)d_in[10];
  const float* W_top = (const float*)d_in[11];
  const float* b_top = (const float*)d_in[12];
  const float* W_full = (const float*)d_in[13];
  const float* b_full = (const float*)d_in[14];  (void)b_full;  // cancels in softmax
  const float* emb   = (const float*)d_in[15];
  const float* W_ih1 = (const float*)d_in[16];
  const float* W_hh1 = (const float*)d_in[17];
  const float* b_ih1 = (const float*)d_in[18];
  const float* b_hh1 = (const float*)d_in[19];
  const float* W_ih2 = (const float*)d_in[20];
  const float* W_hh2 = (const float*)d_in[21];
  const float* b_ih2 = (const float*)d_in[22];
  const float* b_hh2 = (const float*)d_in[23];
  const float* W_fc1 = (const float*)d_in[24];
  const float* b_fc1 = (const float*)d_in[25];
  const float* W_fc  = (const float*)d_in[26];
  const float* b_fc  = (const float*)d_in[27];
  float* out = (float*)d_out;

  char* ws = (char*)d_ws;
  size_t off = 0;
  auto alloc = [&](size_t bytes) -> size_t {
    size_t o = off; off = (off + bytes + 255) & ~(size_t)255; return o;
  };
  const size_t oZERO  = off;                         // ---- zero block start
  const size_t oXimg  = alloc(1568ull * 4096 * 2);
  const size_t oXmean = alloc(112ull * 4096 * 2);
  const size_t oX1    = alloc(112ull * 2048 * 2);    // [h2 | h1] bf16
  const size_t oX2    = alloc(112ull * 6144 * 2);    // [awe | h1 | h2prev] bf16
  const size_t oXh1   = alloc(112ull * 1024 * 2);
  const size_t oXh2   = alloc(112ull * 1024 * 2);
  const size_t oc1    = alloc(100ull * 1024 * 4);
  const size_t oc2    = alloc(100ull * 1024 * 4);
  const size_t zeroBytes = off - oZERO;              // ---- zero block end
  const size_t oXemb  = alloc(560ull * 1024 * 2);
  const size_t olin   = alloc(1568ull * 1024 * 4);
  const size_t otop   = alloc(100ull * 2500 * 4);
  const size_t oXtop  = alloc(560ull * 512 * 2);
  const size_t oTtopb = alloc(560ull * 512 * 2);
  const size_t oatt1  = alloc(1568ull * 512 * 4);
  const size_t ogb1   = alloc(112ull * 4096 * 4);
  const size_t ogemb  = alloc(560ull * 4096 * 4);
  const size_t owords = alloc(512ull * 4);
  const size_t opg    = alloc(6ull * 112 * 4096 * 2);   // gate partials (bf16)
  const size_t opadec = alloc(112ull * 512 * 2);
  const size_t oWg1   = alloc(4096ull * 2048 * 2);      // [Wih1.h2 | Whh1]
  const size_t oWg2   = alloc(4096ull * 6144 * 2);      // [Wih2 | Whh2]
  const size_t oWtopb = alloc(512ull * 512 * 2);
  if (ws_size < off) return;  // insufficient scratch — loud fail

  unsigned short* Ximg  = (unsigned short*)(ws + oXimg);
  unsigned short* Xmean = (unsigned short*)(ws + oXmean);
  unsigned short* Xemb  = (unsigned short*)(ws + oXemb);
  unsigned short* X1    = (unsigned short*)(ws + oX1);
  unsigned short* X2    = (unsigned short*)(ws + oX2);
  unsigned short* Xh1   = (unsigned short*)(ws + oXh1);
  unsigned short* Xh2   = (unsigned short*)(ws + oXh2);
  float* c1    = (float*)(ws + oc1);
  float* c2    = (float*)(ws + oc2);
  float* lin   = (float*)(ws + olin);
  float* topics = (float*)(ws + otop);
  unsigned short* Xtop  = (unsigned short*)(ws + oXtop);
  unsigned short* Ttopb = (unsigned short*)(ws + oTtopb);
  float* att1  = (float*)(ws + oatt1);
  float* gb1   = (float*)(ws + ogb1);
  float* gemb  = (float*)(ws + ogemb);
  int*   words = (int*)(ws + owords);
  unsigned short* pg    = (unsigned short*)(ws + opg);
  unsigned short* padec = (unsigned short*)(ws + opadec);
  unsigned short* Wg1   = (unsigned short*)(ws + oWg1);
  unsigned short* Wg2   = (unsigned short*)(ws + oWg2);
  unsigned short* Wtopb = (unsigned short*)(ws + oWtopb);

  const long long S4 = 112ll * 4096;   // gate partial slot stride

  hipMemsetAsync(ws + oZERO, 0, zeroBytes, stream);

  // -------- phase A (once) --------
  k_ximg2<<<1600, 256, 0, stream>>>(imgf, Ximg, Xmean);
  k_pack_all<<<33024, 256, 0, stream>>>(W_ih1, W_hh1, W_ih2, W_hh2, W_top,
                                        Wg1, Wg2, Wtopb);
  // lin = img @ W_lt^T + b_lt (direct f32, K=4096)
  gemm_dwf<16><<<dim3(16, 14, 1), 256, 0, stream>>>(Ximg, 4096, W_lt, 4096, 1024,
                                                    lin, b_lt, 1024, 1568);
  k_conv<<<100, 512, 0, stream>>>(lin, convw, convb, topics);
  k_padtop<<<1120, 256, 0, stream>>>(topics, Xtop);
  // ttop (bf16 out), K=512
  gemm_v5<2><<<dim3(8, 5, 1), 256, 0, stream>>>(Xtop, 512, Wtopb, 512, 512, Ttopb, 0);
  // att1 = img @ W_feat^T + b_feat (direct f32, K=4096)
  gemm_dwf<16><<<dim3(8, 14, 1), 256, 0, stream>>>(Ximg, 4096, W_feat, 4096, 512,
                                                   att1, b_feat, 512, 1568);
  k_wc<<<102, 256, 0, stream>>>(caps, lens, words, out + 10000000, out + 10026000);
  k_gather<<<2240, 256, 0, stream>>>(emb, words, Xemb);
  // img_mean panel of W_ih1 (f32, split-K z=4, bf16 partials)
  gemm_v5f<4><<<dim3(64, 1, 4), 256, 0, stream>>>(Xmean, 4096, W_ih1 + 1024, 6144, 4096,
                                                  pg, S4);
  k_gbase1<<<1792, 256, 0, stream>>>(pg, b_ih1, b_hh1, gb1);
  // emb panel of W_ih1 (direct f32, all 5 steps, K=1024)
  gemm_dwf<4><<<dim3(64, 5, 1), 256, 0, stream>>>(Xemb, 1024, W_ih1 + 5120, 6144, 4096,
                                                  gemb, nullptr, 4096, 560);

  // -------- recurrent steps --------
  for (int t = 0; t < 5; ++t) {
    // gates1 = Wg1 @ [h2|h1prev]: K=2048, z=4 (NKC=2)
    gemm_v5<2><<<dim3(64, 1, 4), 256, 0, stream>>>(X1, 2048, Wg1, 2048, 4096, pg, S4);
    k_lstm1<<<400, 256, 0, stream>>>(pg, gb1, gemb, t, c1, Xh1, X1, X2);
    // [preds1 -> out | adec -> padec] = Xh1 @ [W_fc1;W_dec]^T (direct, K=1024)
    gemm_dwf_split<4><<<dim3(165, 1, 1), 256, 0, stream>>>(
        Xh1, 1024, W_fc1, W_dec, out + 5000000 + t * 10000, b_fc1, padec);
    k_attawe<<<100, 256, 0, stream>>>(att1, padec, b_dec, b_top, Ttopb, W_full, t,
                                      Ximg, X2);
    // gates2 = Wg2 @ [awe|h1|h2prev]: K=6144, z=6 (NKC=4)
    gemm_v5<4><<<dim3(64, 1, 6), 256, 0, stream>>>(X2, 6144, Wg2, 6144, 4096, pg, S4);
    k_lstm2<<<400, 256, 0, stream>>>(pg, b_ih2, b_hh2, c2, Xh2, X1, X2);
    // preds = Xh2 @ W_fc^T + b_fc (direct f32, K=1024)
    gemm_dwf<4><<<dim3(157, 1, 1), 256, 0, stream>>>(Xh2, 1024, W_fc, 1024, 10000,
                                                     out + t * 10000, b_fc, 50000, 100);
  }
}